// Round 1
// baseline (151.633 us; speedup 1.0000x reference)
//
#include <hip/hip_runtime.h>

// SPIKE layer: x [B,T,C,H,W] f32, thresh_inner/outer [T,1] f32.
// Per spatial site: mem += x[t]; spike = (mem >= inner[t]*T) ? outer[t]*T : 0;
// out[t] = spike; mem -= spike.  T=8 sequential, sites fully parallel.
// Memory-bound: 411 MB read + 411 MB write -> ~130 us roofline at 6.3 TB/s.

#define T_STEPS 8
#define CHW     802816   // 256*56*56
#define CHW_V   200704   // CHW/4 (float4 units)

__global__ __launch_bounds__(256) void spike_scan_kernel(
    const float* __restrict__ x,
    const float* __restrict__ th_inner,
    const float* __restrict__ th_outer,
    float* __restrict__ out)
{
    // Per-step firing threshold and spike amplitude (wave-uniform -> s_loads).
    float innT[T_STEPS], outT[T_STEPS];
#pragma unroll
    for (int t = 0; t < T_STEPS; ++t) {
        innT[t] = th_inner[t] * (float)T_STEPS;
        outT[t] = th_outer[t] * (float)T_STEPS;
    }

    const long long b     = blockIdx.y;
    const long long chw_v = (long long)blockIdx.x * blockDim.x + threadIdx.x;
    const long long base  = b * (long long)T_STEPS * CHW_V + chw_v;

    const float4* __restrict__ xv = reinterpret_cast<const float4*>(x);
    float4* __restrict__ ov       = reinterpret_cast<float4*>(out);

    float4 mem = make_float4(0.f, 0.f, 0.f, 0.f);
#pragma unroll
    for (int t = 0; t < T_STEPS; ++t) {
        const float4 v = xv[base + (long long)t * CHW_V];
        mem.x += v.x; mem.y += v.y; mem.z += v.z; mem.w += v.w;
        float4 sp;
        sp.x = (mem.x >= innT[t]) ? outT[t] : 0.f;
        sp.y = (mem.y >= innT[t]) ? outT[t] : 0.f;
        sp.z = (mem.z >= innT[t]) ? outT[t] : 0.f;
        sp.w = (mem.w >= innT[t]) ? outT[t] : 0.f;
        ov[base + (long long)t * CHW_V] = sp;
        mem.x -= sp.x; mem.y -= sp.y; mem.z -= sp.z; mem.w -= sp.w;
    }
}

extern "C" void kernel_launch(void* const* d_in, const int* in_sizes, int n_in,
                              void* d_out, int out_size, void* d_ws, size_t ws_size,
                              hipStream_t stream) {
    const float* x     = (const float*)d_in[0];
    const float* inner = (const float*)d_in[1];
    const float* outer = (const float*)d_in[2];
    float* out         = (float*)d_out;

    const int B = in_sizes[0] / (T_STEPS * CHW);   // 16
    dim3 grid(CHW_V / 256, B, 1);                  // (784, 16)
    spike_scan_kernel<<<grid, 256, 0, stream>>>(x, inner, outer, out);
}

// Round 2
// 138.129 us; speedup vs baseline: 1.0978x; 1.0978x over previous
//
#include <hip/hip_runtime.h>

// SPIKE layer: x [B,T,C,H,W] f32, thresh_inner/outer [T,1] f32.
// Per spatial site: mem += x[t]; spike = (mem >= inner[t]*T) ? outer[t]*T : 0;
// out[t] = spike; mem -= spike.  T=8 sequential, sites fully parallel.
// Memory-bound: 411 MB read + 411 MB write, touch-once -> nontemporal on both
// sides to avoid L2/L3 allocation thrash (working set 3.2x the 256MB L3).

#define T_STEPS 8
#define CHW     802816   // 256*56*56
#define CHW_V   200704   // CHW/4 (float4 units)

typedef float f32x4 __attribute__((ext_vector_type(4)));

__global__ __launch_bounds__(256) void spike_scan_kernel(
    const float* __restrict__ x,
    const float* __restrict__ th_inner,
    const float* __restrict__ th_outer,
    float* __restrict__ out)
{
    // Per-step firing threshold and spike amplitude (wave-uniform -> s_loads).
    float innT[T_STEPS], outT[T_STEPS];
#pragma unroll
    for (int t = 0; t < T_STEPS; ++t) {
        innT[t] = th_inner[t] * (float)T_STEPS;
        outT[t] = th_outer[t] * (float)T_STEPS;
    }

    const long long b     = blockIdx.y;
    const long long chw_v = (long long)blockIdx.x * blockDim.x + threadIdx.x;
    const long long base  = b * (long long)T_STEPS * CHW_V + chw_v;

    const f32x4* __restrict__ xv = reinterpret_cast<const f32x4*>(x);
    f32x4* __restrict__ ov       = reinterpret_cast<f32x4*>(out);

    f32x4 mem = (f32x4)(0.f);
#pragma unroll
    for (int t = 0; t < T_STEPS; ++t) {
        const f32x4 v = __builtin_nontemporal_load(&xv[base + (long long)t * CHW_V]);
        mem += v;
        f32x4 sp;
        sp.x = (mem.x >= innT[t]) ? outT[t] : 0.f;
        sp.y = (mem.y >= innT[t]) ? outT[t] : 0.f;
        sp.z = (mem.z >= innT[t]) ? outT[t] : 0.f;
        sp.w = (mem.w >= innT[t]) ? outT[t] : 0.f;
        __builtin_nontemporal_store(sp, &ov[base + (long long)t * CHW_V]);
        mem -= sp;
    }
}

extern "C" void kernel_launch(void* const* d_in, const int* in_sizes, int n_in,
                              void* d_out, int out_size, void* d_ws, size_t ws_size,
                              hipStream_t stream) {
    const float* x     = (const float*)d_in[0];
    const float* inner = (const float*)d_in[1];
    const float* outer = (const float*)d_in[2];
    float* out         = (float*)d_out;

    const int B = in_sizes[0] / (T_STEPS * CHW);   // 16
    dim3 grid(CHW_V / 256, B, 1);                  // (784, 16)
    spike_scan_kernel<<<grid, 256, 0, stream>>>(x, inner, outer, out);
}